// Round 1
// 146.657 us; speedup vs baseline: 1.0316x; 1.0316x over previous
//
#include <hip/hip_runtime.h>
#include <hip/hip_bf16.h>

// B=8, S=2048, E=1024, H=64. fp32 in/out, bf16 MFMA compute.
// conv_w: W->bf16, PRE-SWIZZLED (16B unit ^= row&7 within each 64-elem group)
// so qkv staging is a linear copy. qkv_mfma v2: 64x192 tile, 256 blocks
// (1/CU), 4 waves in 2x2 grid (wave tile 32x96), BK=64, double-buffered LDS
// with ONE barrier per K-step (prefetch flies across the whole compute
// phase), XOR-swizzled LDS for conflict-free ds_read_b128 frags. K and Vt
// stored XOR-SWIZZLED for the attention kernel (unchanged layouts).
// attn_mfma: chunk K/V staged to LDS once per block, shared by 4 waves;
// supertile pair (p,31-p), parity-split chunks, fixed-max additive softmax,
// partials to out/ws. attn_fin: merge + normalize.

#define BB 8
#define SS 2048
#define EE 1024
#define HH 64
#define MM (BB * SS)

typedef __bf16 bf16;
typedef __attribute__((ext_vector_type(8))) __bf16 bf16x8;
typedef __attribute__((ext_vector_type(4))) __bf16 bf16x4;
typedef __attribute__((ext_vector_type(4))) float f32x4;
typedef __attribute__((ext_vector_type(4))) short short4v;

// ---------------------------------------------------------------------------
// [Wq;Wk;Wv] (192x1024 fp32) -> Wb (bf16), swizzled: within each 64-elem
// k-group, 8-elem unit u stored at slot u ^ (row&7). 96 blocks.
// ---------------------------------------------------------------------------
__global__ __launch_bounds__(256) void conv_w(const float* __restrict__ Wq,
                                              const float* __restrict__ Wk,
                                              const float* __restrict__ Wv,
                                              bf16* __restrict__ Wb) {
    int i = (blockIdx.x * 256 + threadIdx.x) * 8;
    const float* src;
    int j;
    if (i < 65536)        { src = Wq; j = i; }
    else if (i < 131072)  { src = Wk; j = i - 65536; }
    else                  { src = Wv; j = i - 131072; }
    f32x4 a = *(const f32x4*)(src + j);
    f32x4 b = *(const f32x4*)(src + j + 4);
    bf16x8 o = {(bf16)a.x, (bf16)a.y, (bf16)a.z, (bf16)a.w,
                (bf16)b.x, (bf16)b.y, (bf16)b.z, (bf16)b.w};
    int r   = i >> 10;          // row 0..191
    int kk  = i & 1023;         // element within row (unit-aligned)
    int dst = (r << 10) + (kk & ~63) + ((((kk >> 3) & 7) ^ (r & 7)) << 3);
    *(bf16x8*)(Wb + dst) = o;
}

// ---------------------------------------------------------------------------
// QKV GEMM v2. Block = 256 thr (4 waves, 2x2 wave grid), m-tile 64, n=192,
// BK=64, 16 K-steps. Double-buffered LDS, ONE __syncthreads per K-step:
//   write staged regs -> buf[cur]; barrier; issue next-tile global loads;
//   compute buf[cur].  (Writes of iter t+1 target buf[cur^1], whose last
//   readers finished before barrier_t -> second barrier not needed.)
// A (x fp32) reg-staged + cvt to bf16, XOR-swizzle on LDS write; W staged as
// a LINEAR copy of the pre-swizzled Wb. Frag reads apply u ^= (row&7).
// k0 starts at a per-block phase (anti channel-camping, x rows 4KB-strided).
// K/Vt written with the attention kernel's swizzled layouts (unchanged).
// ---------------------------------------------------------------------------
__global__ __launch_bounds__(256) void qkv_mfma(
    const float* __restrict__ x, const bf16* __restrict__ Wb,
    const float* __restrict__ bq, const float* __restrict__ bk,
    const float* __restrict__ bv,
    bf16* __restrict__ Q, bf16* __restrict__ K, bf16* __restrict__ Vt) {
    __shared__ __align__(16) bf16 As[2][64][64];    // 16 KB, swizzled units
    __shared__ __align__(16) bf16 Ws[2][192][64];   // 48 KB, pre-swizzled

    const int tid  = threadIdx.x;
    const int wave = tid >> 6;
    const int lane = tid & 63;
    const int col  = lane & 15;
    const int quad = lane >> 4;
    const int wm   = wave >> 1;                 // 0..1 (m half)
    const int wn   = wave & 1;                  // 0..1 (n half)
    const int m0   = blockIdx.x * 64;
    const int kph  = (blockIdx.x & 15) << 6;    // k0 phase 0,64,...,960

    // A staging: thread t -> row t>>2, k-quarter (t&3)*16 fp32 (units 2t&3.. )
    const int arow = tid >> 2;                  // 0..63
    const int akq  = (tid & 3) << 4;            // fp32 elem offset 0/16/32/48
    const int au0  = (tid & 3) << 1;            // unit 0/2/4/6
    const int asw0 = ((au0 ^ (arow & 7)) << 3);
    const int asw1 = (((au0 + 1) ^ (arow & 7)) << 3);
    // W staging: thread t -> rows (t>>3)+32*i, unit t&7 (linear copy)
    const int wrow = tid >> 3;                  // 0..31
    const int wu   = (tid & 7) << 3;            // elem offset of unit

    f32x4 acc[2][6];
#pragma unroll
    for (int mt = 0; mt < 2; mt++)
#pragma unroll
        for (int nt = 0; nt < 6; nt++) acc[mt][nt] = {0.f, 0.f, 0.f, 0.f};

    // prologue: tile 0 into regs
    f32x4 areg[4];
    bf16x8 wreg[6];
#pragma unroll
    for (int q = 0; q < 4; q++)
        areg[q] = *(const f32x4*)&x[(size_t)(m0 + arow) * EE + kph + akq + q * 4];
#pragma unroll
    for (int i = 0; i < 6; i++)
        wreg[i] = *(const bf16x8*)&Wb[(size_t)(wrow + 32 * i) * EE + kph + wu];

    for (int it = 0; it < 16; it++) {
        const int cur = it & 1;
        // commit staged regs to LDS buffer `cur`
        bf16x8 a0 = {(bf16)areg[0].x, (bf16)areg[0].y, (bf16)areg[0].z, (bf16)areg[0].w,
                     (bf16)areg[1].x, (bf16)areg[1].y, (bf16)areg[1].z, (bf16)areg[1].w};
        bf16x8 a1 = {(bf16)areg[2].x, (bf16)areg[2].y, (bf16)areg[2].z, (bf16)areg[2].w,
                     (bf16)areg[3].x, (bf16)areg[3].y, (bf16)areg[3].z, (bf16)areg[3].w};
        *(bf16x8*)&As[cur][arow][asw0] = a0;
        *(bf16x8*)&As[cur][arow][asw1] = a1;
#pragma unroll
        for (int i = 0; i < 6; i++)
            *(bf16x8*)&Ws[cur][wrow + 32 * i][wu] = wreg[i];
        __syncthreads();  // buf[cur] visible; prev readers of buf[cur^1] done

        // issue next tile's loads AFTER the barrier: they fly across the
        // whole compute phase before their vmcnt wait at next iter's top
        if (it < 15) {
            int k0n = (kph + (it + 1) * 64) & 1023;
#pragma unroll
            for (int q = 0; q < 4; q++)
                areg[q] = *(const f32x4*)&x[(size_t)(m0 + arow) * EE + k0n + akq + q * 4];
#pragma unroll
            for (int i = 0; i < 6; i++)
                wreg[i] = *(const bf16x8*)&Wb[(size_t)(wrow + 32 * i) * EE + k0n + wu];
        }

        // compute: 24 MFMA / wave, 16 swizzled ds_read_b128
#pragma unroll
        for (int kk = 0; kk < 64; kk += 32) {
            const int ub = (kk >> 3) + quad;    // k-unit of this fragment
            bf16x8 af[2];
#pragma unroll
            for (int mt = 0; mt < 2; mt++) {
                int r = wm * 32 + mt * 16 + col;
                af[mt] = *(const bf16x8*)&As[cur][r][(ub ^ (r & 7)) << 3];
            }
#pragma unroll
            for (int nt = 0; nt < 6; nt++) {
                int rn = wn * 96 + nt * 16 + col;
                bf16x8 bg = *(const bf16x8*)&Ws[cur][rn][(ub ^ (rn & 7)) << 3];
                acc[0][nt] = __builtin_amdgcn_mfma_f32_16x16x32_bf16(af[0], bg, acc[0][nt], 0, 0, 0);
                acc[1][nt] = __builtin_amdgcn_mfma_f32_16x16x32_bf16(af[1], bg, acc[1][nt], 0, 0, 0);
            }
        }
    }

    // epilogue: same store math as v1, new tile ownership
#pragma unroll
    for (int mt = 0; mt < 2; mt++) {
        const int mr0  = m0 + wm * 32 + mt * 16 + quad * 4;
        const int bidx = mr0 >> 11;
        const int sloc = mr0 & 2047;
        const int ck   = sloc >> 6;
        const int so   = sloc & 63;
#pragma unroll
        for (int nt = 0; nt < 6; nt++) {
            const int n = wn * 96 + nt * 16;
            const int g = n >> 6;               // 0=Q 1=K 2=V (wave-uniform)
            const int h = (n & 63) + col;
            if (g == 0) {
                float bias = bq[h];
#pragma unroll
                for (int r = 0; r < 4; r++)
                    Q[(size_t)(mr0 + r) * HH + h] = (bf16)((acc[mt][nt][r] + bias) * 0.125f);
            } else if (g == 1) {
                float bias = bk[h];
#pragma unroll
                for (int r = 0; r < 4; r++) {
                    int s = mr0 + r;                     // swizzled K store
                    int u = (h >> 3) ^ (s & 7);
                    K[(size_t)s * HH + u * 8 + (h & 7)] = (bf16)(acc[mt][nt][r] + bias);
                }
            } else {
                float bias = bv[h];
                bf16x4 pk = {(bf16)(acc[mt][nt][0] + bias), (bf16)(acc[mt][nt][1] + bias),
                             (bf16)(acc[mt][nt][2] + bias), (bf16)(acc[mt][nt][3] + bias)};
                int u = (so >> 3) ^ (h & 7);             // swizzled Vt store
                *(bf16x4*)&Vt[(size_t)bidx * SS * HH + (size_t)ck * 4096 +
                              h * 64 + u * 8 + (so & 7)] = pk;
            }
        }
    }
}

// ---------------------------------------------------------------------------
// Flash attention, LDS-shared chunks. Block = 256 thr (4 waves); supertile
// pair lo=p (64 rows), hi=31-p; wave w owns 16-row subtile of each. Unified
// chunk list j=0..32 (j<nlo -> lo chunk j, else hi chunk j-nlo); block par
// takes j===par (mod 2). Per chunk: 16KB K/V staged to LDS (coalesced,
// double-buffered, ONE barrier), all 4 waves compute their subtile from LDS
// (XOR-swizzled reads, 2-way conflicts = free). Transposed-S + fixed-max
// softmax + register PV. Partials (o,l): par0 -> out/l0, par1 -> o1/l1.
// ---------------------------------------------------------------------------
__global__ __launch_bounds__(256) void attn_mfma(
    const bf16* __restrict__ Q, const bf16* __restrict__ K,
    const bf16* __restrict__ Vt, float* __restrict__ o0,
    float* __restrict__ o1, float* __restrict__ l0, float* __restrict__ l1) {
    __shared__ __align__(16) bf16 kv[2][8192];  // 32 KB: [buf][K 4096 | V 4096]

    const int p    = blockIdx.x;      // 0..15
    const int b    = blockIdx.y;
    const int par  = blockIdx.z;      // 0..1
    const int tid  = threadIdx.x;
    const int wave = tid >> 6;
    const int lane = tid & 63;
    const int col  = lane & 15;
    const int quad = lane >> 4;

    const int nlo = p + 1, nhi = 32 - p;          // nlo + nhi == 33
    const int lo0 = p * 64 + wave * 16;
    const int hi0 = (31 - p) * 64 + wave * 16;

    const bf16* Qb = Q + (size_t)b * SS * HH;
    const bf16* Kb = K + (size_t)b * SS * HH;
    const bf16* Vb = Vt + (size_t)b * SS * HH;

    bf16x8 qlo0 = *(const bf16x8*)&Qb[(size_t)(lo0 + col) * HH + quad * 8];
    bf16x8 qlo1 = *(const bf16x8*)&Qb[(size_t)(lo0 + col) * HH + 32 + quad * 8];
    bf16x8 qhi0 = *(const bf16x8*)&Qb[(size_t)(hi0 + col) * HH + quad * 8];
    bf16x8 qhi1 = *(const bf16x8*)&Qb[(size_t)(hi0 + col) * HH + 32 + quad * 8];

    f32x4 olo[4], ohi[4];
#pragma unroll
    for (int n = 0; n < 4; n++) {
        olo[n] = {0.f, 0.f, 0.f, 0.f};
        ohi[n] = {0.f, 0.f, 0.f, 0.f};
    }
    float llo = 0.f, lhi = 0.f;

    // prefetch first chunk into registers (16KB/block = 64B/thread)
    bf16x8 greg[4];
    {
        int c0 = (par >= nlo) ? par - nlo : par;
#pragma unroll
        for (int i = 0; i < 4; i++) {
            const bf16* g = (i < 2) ? Kb + (size_t)c0 * 4096 + i * 2048
                                    : Vb + (size_t)c0 * 4096 + (i - 2) * 2048;
            greg[i] = *(const bf16x8*)(g + tid * 8);
        }
    }

    int idx = 0;
    for (int j = par; j < 33; j += 2, idx++) {
        const int isHi = (j >= nlo);
        const int c    = isHi ? j - nlo : j;
        const int cur  = idx & 1;

        // commit staged regs to LDS buffer `cur` (safe: last read of `cur`
        // finished before the previous iteration's barrier)
#pragma unroll
        for (int i = 0; i < 4; i++)
            *(bf16x8*)&kv[cur][i * 2048 + tid * 8] = greg[i];

        // prefetch next chunk (flies during this chunk's compute)
        const int jn = j + 2;
        if (jn < 33) {
            int c2 = (jn >= nlo) ? jn - nlo : jn;
#pragma unroll
            for (int i = 0; i < 4; i++) {
                const bf16* g = (i < 2) ? Kb + (size_t)c2 * 4096 + i * 2048
                                        : Vb + (size_t)c2 * 4096 + (i - 2) * 2048;
                greg[i] = *(const bf16x8*)(g + tid * 8);
            }
        }
        __syncthreads();  // kv[cur] visible to all waves

        const bf16* lk = &kv[cur][0];
        const bf16* lv = &kv[cur][4096];
        const bf16x8 qb0 = isHi ? qhi0 : qlo0;
        const bf16x8 qb1 = isHi ? qhi1 : qlo1;

        f32x4 s[4];
#pragma unroll
        for (int n4 = 0; n4 < 4; n4++) {
            int sr = n4 * 16 + col;
            bf16x8 ka0 = *(const bf16x8*)&lk[sr * 64 + ((quad ^ (sr & 7)) * 8)];
            bf16x8 ka1 = *(const bf16x8*)&lk[sr * 64 + (((4 + quad) ^ (sr & 7)) * 8)];
            f32x4 z = {0.f, 0.f, 0.f, 0.f};
            z     = __builtin_amdgcn_mfma_f32_16x16x32_bf16(ka0, qb0, z, 0, 0, 0);
            s[n4] = __builtin_amdgcn_mfma_f32_16x16x32_bf16(ka1, qb1, z, 0, 0, 0);
        }

        const int  nch  = isHi ? nhi : nlo;
        const int  qrow = (isHi ? hi0 : lo0) + col;
        const bool diag = (c == nch - 1);
        float rs = 0.f;
        short4v p4[4];
#pragma unroll
        for (int n4 = 0; n4 < 4; n4++) {
            bf16x4 pb;
#pragma unroll
            for (int r = 0; r < 4; r++) {
                float pe = __expf(s[n4][r]);
                if (diag) {
                    int kr = c * 64 + n4 * 16 + quad * 4 + r;
                    if (kr > qrow) pe = 0.f;
                }
                rs += pe;
                pb[r] = (bf16)pe;
            }
            p4[n4] = __builtin_bit_cast(short4v, pb);
        }

        if (!isHi) {
            llo += rs;
#pragma unroll
            for (int h4 = 0; h4 < 4; h4++)
#pragma unroll
                for (int n4 = 0; n4 < 4; n4++) {
                    int vr = h4 * 16 + col;
                    int u  = n4 * 2 + (quad >> 1);
                    bf16x4 vv = *(const bf16x4*)&lv[vr * 64 + ((u ^ (vr & 7)) * 8) +
                                                    (quad & 1) * 4];
                    olo[h4] = __builtin_amdgcn_mfma_f32_16x16x16bf16_1k(
                        p4[n4], __builtin_bit_cast(short4v, vv), olo[h4], 0, 0, 0);
                }
        } else {
            lhi += rs;
#pragma unroll
            for (int h4 = 0; h4 < 4; h4++)
#pragma unroll
                for (int n4 = 0; n4 < 4; n4++) {
                    int vr = h4 * 16 + col;
                    int u  = n4 * 2 + (quad >> 1);
                    bf16x4 vv = *(const bf16x4*)&lv[vr * 64 + ((u ^ (vr & 7)) * 8) +
                                                    (quad & 1) * 4];
                    ohi[h4] = __builtin_amdgcn_mfma_f32_16x16x16bf16_1k(
                        p4[n4], __builtin_bit_cast(short4v, vv), ohi[h4], 0, 0, 0);
                }
        }
    }

    // l: reduce across the 4 quads (same q = col); direct global partials
    llo += __shfl_xor(llo, 16); llo += __shfl_xor(llo, 32);
    lhi += __shfl_xor(lhi, 16); lhi += __shfl_xor(lhi, 32);
    float* od = par ? o1 : o0;
    float* ld = par ? l1 : l0;
    if (quad == 0) {
        ld[b * SS + lo0 + col] = llo;
        ld[b * SS + hi0 + col] = lhi;
    }
#pragma unroll
    for (int h4 = 0; h4 < 4; h4++)
#pragma unroll
        for (int r = 0; r < 4; r++) {
            od[((size_t)b * SS + lo0 + quad * 4 + r) * HH + h4 * 16 + col] = olo[h4][r];
            od[((size_t)b * SS + hi0 + quad * 4 + r) * HH + h4 * 16 + col] = ohi[h4][r];
        }
}

// ---------------------------------------------------------------------------
// Merge the two parity partials: out = (out + o1) / (l0 + l1). 1024 blocks.
// ---------------------------------------------------------------------------
__global__ __launch_bounds__(256) void attn_fin(float* __restrict__ out,
                                                const float* __restrict__ o1,
                                                const float* __restrict__ l0,
                                                const float* __restrict__ l1) {
    int i   = blockIdx.x * 256 + threadIdx.x;  // f32x4 index, 262144 total
    int row = i >> 4;
    float inv = 1.f / (l0[row] + l1[row]);
    f32x4 a  = *(f32x4*)&out[i * 4];
    f32x4 bb = *(const f32x4*)&o1[i * 4];
    a = (a + bb) * inv;
    *(f32x4*)&out[i * 4] = a;
}

extern "C" void kernel_launch(void* const* d_in, const int* in_sizes, int n_in,
                              void* d_out, int out_size, void* d_ws, size_t ws_size,
                              hipStream_t stream) {
    const float* x  = (const float*)d_in[0];
    const float* Wq = (const float*)d_in[1];
    const float* bq = (const float*)d_in[2];
    const float* Wk = (const float*)d_in[3];
    const float* bk = (const float*)d_in[4];
    const float* Wv = (const float*)d_in[5];
    const float* bv = (const float*)d_in[6];
    float* out = (float*)d_out;

    bf16*  Q  = (bf16*)d_ws;                   // 2 MB
    bf16*  K  = Q + (size_t)MM * HH;           // 2 MB (swizzled)
    bf16*  Vt = K + (size_t)MM * HH;           // 2 MB (chunk-tiled, swizzled)
    bf16*  Wb = Vt + (size_t)MM * HH;          // 384 KB (pre-swizzled)
    float* o1 = (float*)(Wb + (size_t)192 * EE);  // 4 MB (par1 partial o)
    float* l0 = o1 + (size_t)MM * HH;          // 64 KB
    float* l1 = l0 + MM;                       // 64 KB  (total ~11.0 MB)

    conv_w<<<96, 256, 0, stream>>>(Wq, Wk, Wv, Wb);
    qkv_mfma<<<MM / 64, 256, 0, stream>>>(x, Wb, bq, bk, bv, Q, K, Vt);
    dim3 g(16, BB, 2);
    attn_mfma<<<g, 256, 0, stream>>>(Q, K, Vt, out, o1, l0, l1);
    attn_fin<<<1024, 256, 0, stream>>>(out, o1, l0, l1);
}

// Round 2
// 135.486 us; speedup vs baseline: 1.1167x; 1.0825x over previous
//
#include <hip/hip_runtime.h>
#include <hip/hip_bf16.h>

// B=8, S=2048, E=1024, H=64. fp32 in/out, bf16 MFMA compute.
// conv_w: W->bf16, PRE-SWIZZLED (16B unit ^= row&7 within each 64-elem group)
// so qkv staging is a linear copy. qkv_mfma v3: 64x192 tile, 256 blocks,
// 512 THREADS (8 waves, 2x4 grid, wave tile 32x48) -> 2 waves/SIMD for
// latency hiding; BK=64, double-buffered LDS, ONE barrier per K-step,
// XOR-swizzled LDS for conflict-free ds_read_b128. K/Vt stored XOR-swizzled
// for attention (unchanged layouts). attn_mfma v3: supertile pair SPLIT
// across blockIdx.z (sel=lo/hi x parity) -> 512 blocks = 2 blocks/CU;
// per-block chunks halve, regs halve. Chunk K/V staged to LDS, shared by
// 4 waves, double-buffered, one barrier; transposed-S fixed-max additive
// softmax; partials par0->out/l0, par1->o1/l1. attn_fin: merge + normalize.

#define BB 8
#define SS 2048
#define EE 1024
#define HH 64
#define MM (BB * SS)

typedef __bf16 bf16;
typedef __attribute__((ext_vector_type(8))) __bf16 bf16x8;
typedef __attribute__((ext_vector_type(4))) __bf16 bf16x4;
typedef __attribute__((ext_vector_type(4))) float f32x4;
typedef __attribute__((ext_vector_type(4))) short short4v;

// ---------------------------------------------------------------------------
// [Wq;Wk;Wv] (192x1024 fp32) -> Wb (bf16), swizzled: within each 64-elem
// k-group, 8-elem unit u stored at slot u ^ (row&7). 96 blocks.
// ---------------------------------------------------------------------------
__global__ __launch_bounds__(256) void conv_w(const float* __restrict__ Wq,
                                              const float* __restrict__ Wk,
                                              const float* __restrict__ Wv,
                                              bf16* __restrict__ Wb) {
    int i = (blockIdx.x * 256 + threadIdx.x) * 8;
    const float* src;
    int j;
    if (i < 65536)        { src = Wq; j = i; }
    else if (i < 131072)  { src = Wk; j = i - 65536; }
    else                  { src = Wv; j = i - 131072; }
    f32x4 a = *(const f32x4*)(src + j);
    f32x4 b = *(const f32x4*)(src + j + 4);
    bf16x8 o = {(bf16)a.x, (bf16)a.y, (bf16)a.z, (bf16)a.w,
                (bf16)b.x, (bf16)b.y, (bf16)b.z, (bf16)b.w};
    int r   = i >> 10;          // row 0..191
    int kk  = i & 1023;         // element within row (unit-aligned)
    int dst = (r << 10) + (kk & ~63) + ((((kk >> 3) & 7) ^ (r & 7)) << 3);
    *(bf16x8*)(Wb + dst) = o;
}

// ---------------------------------------------------------------------------
// QKV GEMM v3. Block = 512 thr (8 waves, 2x4 wave grid), m-tile 64, n=192,
// BK=64, 16 K-steps, 2 waves/SIMD. Double-buffered LDS, ONE __syncthreads
// per K-step: write staged regs -> buf[cur]; barrier; issue next-tile
// global loads (fly across compute); compute buf[cur]. A (x fp32)
// reg-staged + cvt, XOR-swizzle on LDS write; W staged as a LINEAR copy of
// pre-swizzled Wb. Frag reads apply unit ^= (row&7). k0 per-block phase
// (anti channel-camping). K/Vt written with attention's swizzled layouts.
// ---------------------------------------------------------------------------
__global__ __launch_bounds__(512) void qkv_mfma(
    const float* __restrict__ x, const bf16* __restrict__ Wb,
    const float* __restrict__ bq, const float* __restrict__ bk,
    const float* __restrict__ bv,
    bf16* __restrict__ Q, bf16* __restrict__ K, bf16* __restrict__ Vt) {
    __shared__ __align__(16) bf16 As[2][64][64];    // 16 KB, swizzled units
    __shared__ __align__(16) bf16 Ws[2][192][64];   // 48 KB, pre-swizzled

    const int tid  = threadIdx.x;
    const int wave = tid >> 6;
    const int lane = tid & 63;
    const int col  = lane & 15;
    const int quad = lane >> 4;
    const int wm   = wave >> 2;                 // 0..1 (m half, 32 rows)
    const int wn   = wave & 3;                  // 0..3 (n quarter, 48 cols)
    const int m0   = blockIdx.x * 64;
    const int kph  = (blockIdx.x & 15) << 6;    // k0 phase 0,64,...,960

    // A staging: thread t -> row t>>3, 8 fp32 at elem (t&7)*8 -> one unit
    const int arow = tid >> 3;                  // 0..63
    const int au   = tid & 7;                   // unit 0..7
    const int aoff = au << 3;                   // fp32 elem offset
    const int asw  = (au ^ (arow & 7)) << 3;    // swizzled elem offset
    // W staging: thread t -> rows (t>>3)+64*i (i<3), unit t&7 (linear copy)
    const int wrow = tid >> 3;                  // 0..63
    const int wu   = (tid & 7) << 3;

    f32x4 acc[2][3];
#pragma unroll
    for (int mt = 0; mt < 2; mt++)
#pragma unroll
        for (int nt = 0; nt < 3; nt++) acc[mt][nt] = {0.f, 0.f, 0.f, 0.f};

    // prologue: tile 0 into regs
    f32x4 areg[2];
    bf16x8 wreg[3];
#pragma unroll
    for (int q = 0; q < 2; q++)
        areg[q] = *(const f32x4*)&x[(size_t)(m0 + arow) * EE + kph + aoff + q * 4];
#pragma unroll
    for (int i = 0; i < 3; i++)
        wreg[i] = *(const bf16x8*)&Wb[(size_t)(wrow + 64 * i) * EE + kph + wu];

    for (int it = 0; it < 16; it++) {
        const int cur = it & 1;
        // commit staged regs to LDS buffer `cur`
        bf16x8 a0 = {(bf16)areg[0].x, (bf16)areg[0].y, (bf16)areg[0].z, (bf16)areg[0].w,
                     (bf16)areg[1].x, (bf16)areg[1].y, (bf16)areg[1].z, (bf16)areg[1].w};
        *(bf16x8*)&As[cur][arow][asw] = a0;
#pragma unroll
        for (int i = 0; i < 3; i++)
            *(bf16x8*)&Ws[cur][wrow + 64 * i][wu] = wreg[i];
        __syncthreads();  // buf[cur] visible; prev readers of buf[cur^1] done

        // issue next tile's loads AFTER the barrier: they fly across the
        // whole compute phase before their vmcnt wait at next iter's top
        if (it < 15) {
            int k0n = (kph + (it + 1) * 64) & 1023;
#pragma unroll
            for (int q = 0; q < 2; q++)
                areg[q] = *(const f32x4*)&x[(size_t)(m0 + arow) * EE + k0n + aoff + q * 4];
#pragma unroll
            for (int i = 0; i < 3; i++)
                wreg[i] = *(const bf16x8*)&Wb[(size_t)(wrow + 64 * i) * EE + k0n + wu];
        }

        // compute: 12 MFMA / wave, 10 swizzled ds_read_b128
#pragma unroll
        for (int kk = 0; kk < 64; kk += 32) {
            const int ub = (kk >> 3) + quad;    // k-unit of this fragment
            bf16x8 af[2];
#pragma unroll
            for (int mt = 0; mt < 2; mt++) {
                int r = wm * 32 + mt * 16 + col;
                af[mt] = *(const bf16x8*)&As[cur][r][(ub ^ (r & 7)) << 3];
            }
#pragma unroll
            for (int nt = 0; nt < 3; nt++) {
                int rn = wn * 48 + nt * 16 + col;
                bf16x8 bg = *(const bf16x8*)&Ws[cur][rn][(ub ^ (rn & 7)) << 3];
                acc[0][nt] = __builtin_amdgcn_mfma_f32_16x16x32_bf16(af[0], bg, acc[0][nt], 0, 0, 0);
                acc[1][nt] = __builtin_amdgcn_mfma_f32_16x16x32_bf16(af[1], bg, acc[1][nt], 0, 0, 0);
            }
        }
    }

    // epilogue: same store math, 2x4 wave-grid ownership
#pragma unroll
    for (int mt = 0; mt < 2; mt++) {
        const int mr0  = m0 + wm * 32 + mt * 16 + quad * 4;
        const int bidx = mr0 >> 11;
        const int sloc = mr0 & 2047;
        const int ck   = sloc >> 6;
        const int so   = sloc & 63;
#pragma unroll
        for (int nt = 0; nt < 3; nt++) {
            const int n = wn * 48 + nt * 16;
            const int g = n >> 6;               // 0=Q 1=K 2=V (unrolled-const)
            const int h = (n & 63) + col;
            if (g == 0) {
                float bias = bq[h];
#pragma unroll
                for (int r = 0; r < 4; r++)
                    Q[(size_t)(mr0 + r) * HH + h] = (bf16)((acc[mt][nt][r] + bias) * 0.125f);
            } else if (g == 1) {
                float bias = bk[h];
#pragma unroll
                for (int r = 0; r < 4; r++) {
                    int s = mr0 + r;                     // swizzled K store
                    int u = (h >> 3) ^ (s & 7);
                    K[(size_t)s * HH + u * 8 + (h & 7)] = (bf16)(acc[mt][nt][r] + bias);
                }
            } else {
                float bias = bv[h];
                bf16x4 pk = {(bf16)(acc[mt][nt][0] + bias), (bf16)(acc[mt][nt][1] + bias),
                             (bf16)(acc[mt][nt][2] + bias), (bf16)(acc[mt][nt][3] + bias)};
                int u = (so >> 3) ^ (h & 7);             // swizzled Vt store
                *(bf16x4*)&Vt[(size_t)bidx * SS * HH + (size_t)ck * 4096 +
                              h * 64 + u * 8 + (so & 7)] = pk;
            }
        }
    }
}

// ---------------------------------------------------------------------------
// Flash attention v3. blockIdx = (p 0..15, b, z 0..3) with z = sel*2+par:
// sel picks supertile (lo=p or hi=31-p, 64 q-rows), par picks chunk parity.
// 512 blocks = 2 blocks/CU. Block = 256 thr (4 waves, 16 q-rows each).
// Per chunk: 16KB K/V staged to LDS (coalesced, double-buffered, ONE
// barrier), all 4 waves compute from LDS (XOR-swizzled reads). Transposed-S
// + fixed-max additive softmax + register PV. Partials: par0 -> out/l0,
// par1 -> o1/l1 (each q-row has exactly one writer per parity; zero-chunk
// blocks write zeros, required because ws is poisoned).
// ---------------------------------------------------------------------------
__global__ __launch_bounds__(256) void attn_mfma(
    const bf16* __restrict__ Q, const bf16* __restrict__ K,
    const bf16* __restrict__ Vt, float* __restrict__ o0,
    float* __restrict__ o1, float* __restrict__ l0, float* __restrict__ l1) {
    __shared__ __align__(16) bf16 kv[2][8192];  // 32 KB: [buf][K 4096 | V 4096]

    const int p    = blockIdx.x;      // 0..15
    const int b    = blockIdx.y;
    const int z    = blockIdx.z;      // 0..3
    const int sel  = z >> 1;          // 0=lo supertile, 1=hi
    const int par  = z & 1;           // chunk parity
    const int tid  = threadIdx.x;
    const int wave = tid >> 6;
    const int lane = tid & 63;
    const int col  = lane & 15;
    const int quad = lane >> 4;

    const int st  = sel ? (31 - p) : p;   // supertile index 0..31
    const int nch = st + 1;               // causal chunk count
    const int r0  = st * 64 + wave * 16;  // this wave's q-row base

    const bf16* Qb = Q + (size_t)b * SS * HH;
    const bf16* Kb = K + (size_t)b * SS * HH;
    const bf16* Vb = Vt + (size_t)b * SS * HH;

    bf16x8 q0 = *(const bf16x8*)&Qb[(size_t)(r0 + col) * HH + quad * 8];
    bf16x8 q1 = *(const bf16x8*)&Qb[(size_t)(r0 + col) * HH + 32 + quad * 8];

    f32x4 o[4];
#pragma unroll
    for (int n = 0; n < 4; n++) o[n] = {0.f, 0.f, 0.f, 0.f};
    float l = 0.f;

    // prefetch first chunk into registers (16KB/block = 64B/thread)
    bf16x8 greg[4];
    if (par < nch) {
#pragma unroll
        for (int i = 0; i < 4; i++) {
            const bf16* g = (i < 2) ? Kb + (size_t)par * 4096 + i * 2048
                                    : Vb + (size_t)par * 4096 + (i - 2) * 2048;
            greg[i] = *(const bf16x8*)(g + tid * 8);
        }
    }

    int idx = 0;
    for (int c = par; c < nch; c += 2, idx++) {
        const int cur = idx & 1;

        // commit staged regs to LDS buffer `cur` (safe: last read of `cur`
        // finished before the previous iteration's barrier)
#pragma unroll
        for (int i = 0; i < 4; i++)
            *(bf16x8*)&kv[cur][i * 2048 + tid * 8] = greg[i];

        // prefetch next chunk (flies during this chunk's compute)
        if (c + 2 < nch) {
            int c2 = c + 2;
#pragma unroll
            for (int i = 0; i < 4; i++) {
                const bf16* g = (i < 2) ? Kb + (size_t)c2 * 4096 + i * 2048
                                        : Vb + (size_t)c2 * 4096 + (i - 2) * 2048;
                greg[i] = *(const bf16x8*)(g + tid * 8);
            }
        }
        __syncthreads();  // kv[cur] visible to all waves

        const bf16* lk = &kv[cur][0];
        const bf16* lv = &kv[cur][4096];

        f32x4 s[4];
#pragma unroll
        for (int n4 = 0; n4 < 4; n4++) {
            int sr = n4 * 16 + col;
            bf16x8 ka0 = *(const bf16x8*)&lk[sr * 64 + ((quad ^ (sr & 7)) * 8)];
            bf16x8 ka1 = *(const bf16x8*)&lk[sr * 64 + (((4 + quad) ^ (sr & 7)) * 8)];
            f32x4 zz = {0.f, 0.f, 0.f, 0.f};
            zz    = __builtin_amdgcn_mfma_f32_16x16x32_bf16(ka0, q0, zz, 0, 0, 0);
            s[n4] = __builtin_amdgcn_mfma_f32_16x16x32_bf16(ka1, q1, s[n4] = zz, 0, 0, 0);
        }

        const int  qrow = r0 + col;
        const bool diag = (c == nch - 1);
        float rs = 0.f;
        short4v p4[4];
#pragma unroll
        for (int n4 = 0; n4 < 4; n4++) {
            bf16x4 pb;
#pragma unroll
            for (int r = 0; r < 4; r++) {
                float pe = __expf(s[n4][r]);
                if (diag) {
                    int kr = c * 64 + n4 * 16 + quad * 4 + r;
                    if (kr > qrow) pe = 0.f;
                }
                rs += pe;
                pb[r] = (bf16)pe;
            }
            p4[n4] = __builtin_bit_cast(short4v, pb);
        }

        l += rs;
#pragma unroll
        for (int h4 = 0; h4 < 4; h4++)
#pragma unroll
            for (int n4 = 0; n4 < 4; n4++) {
                int vr = h4 * 16 + col;
                int u  = n4 * 2 + (quad >> 1);
                bf16x4 vv = *(const bf16x4*)&lv[vr * 64 + ((u ^ (vr & 7)) * 8) +
                                                (quad & 1) * 4];
                o[h4] = __builtin_amdgcn_mfma_f32_16x16x16bf16_1k(
                    p4[n4], __builtin_bit_cast(short4v, vv), o[h4], 0, 0, 0);
            }
    }

    // l: reduce across the 4 quads (same q = col); direct global partials
    l += __shfl_xor(l, 16); l += __shfl_xor(l, 32);
    float* od = par ? o1 : o0;
    float* ld = par ? l1 : l0;
    if (quad == 0) ld[b * SS + r0 + col] = l;
#pragma unroll
    for (int h4 = 0; h4 < 4; h4++)
#pragma unroll
        for (int r = 0; r < 4; r++)
            od[((size_t)b * SS + r0 + quad * 4 + r) * HH + h4 * 16 + col] = o[h4][r];
}

// ---------------------------------------------------------------------------
// Merge the two parity partials: out = (out + o1) / (l0 + l1). 1024 blocks.
// ---------------------------------------------------------------------------
__global__ __launch_bounds__(256) void attn_fin(float* __restrict__ out,
                                                const float* __restrict__ o1,
                                                const float* __restrict__ l0,
                                                const float* __restrict__ l1) {
    int i   = blockIdx.x * 256 + threadIdx.x;  // f32x4 index, 262144 total
    int row = i >> 4;
    float inv = 1.f / (l0[row] + l1[row]);
    f32x4 a  = *(f32x4*)&out[i * 4];
    f32x4 bb = *(const f32x4*)&o1[i * 4];
    a = (a + bb) * inv;
    *(f32x4*)&out[i * 4] = a;
}

extern "C" void kernel_launch(void* const* d_in, const int* in_sizes, int n_in,
                              void* d_out, int out_size, void* d_ws, size_t ws_size,
                              hipStream_t stream) {
    const float* x  = (const float*)d_in[0];
    const float* Wq = (const float*)d_in[1];
    const float* bq = (const float*)d_in[2];
    const float* Wk = (const float*)d_in[3];
    const float* bk = (const float*)d_in[4];
    const float* Wv = (const float*)d_in[5];
    const float* bv = (const float*)d_in[6];
    float* out = (float*)d_out;

    bf16*  Q  = (bf16*)d_ws;                   // 2 MB
    bf16*  K  = Q + (size_t)MM * HH;           // 2 MB (swizzled)
    bf16*  Vt = K + (size_t)MM * HH;           // 2 MB (chunk-tiled, swizzled)
    bf16*  Wb = Vt + (size_t)MM * HH;          // 384 KB (pre-swizzled)
    float* o1 = (float*)(Wb + (size_t)192 * EE);  // 4 MB (par1 partial o)
    float* l0 = o1 + (size_t)MM * HH;          // 64 KB
    float* l1 = l0 + MM;                       // 64 KB  (total ~11.0 MB)

    conv_w<<<96, 256, 0, stream>>>(Wq, Wk, Wv, Wb);
    qkv_mfma<<<MM / 64, 512, 0, stream>>>(x, Wb, bq, bk, bv, Q, K, Vt);
    dim3 g(16, BB, 4);
    attn_mfma<<<g, 256, 0, stream>>>(Q, K, Vt, out, o1, l0, l1);
    attn_fin<<<1024, 256, 0, stream>>>(out, o1, l0, l1);
}